// Round 19
// baseline (198.202 us; speedup 1.0000x reference)
//
#include <hip/hip_runtime.h>
#include <hip/hip_bf16.h>

#define VXX 256
#define VYY 256
#define VZZ 20
#define NC  80
#define OH  200
#define OW  200
#define OZ  16
#define SPATIAL (OH*OW*OZ)      // 640000
#define NVOX (VXX*VYY*VZZ)      // 1310720
#define EPSV 1e-5f
#define NS 64                   // spatial positions per tile
#define NTILE (SPATIAL/NS)      // 10000 tiles
#define NB (NTILE/2)            // 5000 blocks, 2 adjacent tiles each
#define X_FOOT 6
#define NCELL (2*X_FOOT*VZZ)    // 240 footprint cells
#define SLOTS 48
#define PSTR 72                 // bf16 per P/Rt row (144 B)
#define RSB 80                  // xb row stride (bf16): 160 B
#define RSP 88                  // xp row stride (bf16): 176 B

typedef float  f32x4 __attribute__((ext_vector_type(4)));
typedef short  s16x8 __attribute__((ext_vector_type(8)));

__device__ __forceinline__ ushort f2bf(float f) {
    uint u = __builtin_bit_cast(uint, f);
    u += 0x7FFFu + ((u >> 16) & 1u);
    return (ushort)(u >> 16);
}

__device__ __forceinline__ void bar_lgkm() {
    asm volatile("s_waitcnt lgkmcnt(0)" ::: "memory");
    __builtin_amdgcn_s_barrier();
    asm volatile("" ::: "memory");
}

__global__ void scatter_k(const int* __restrict__ coords, int npts,
                          int* __restrict__ winner) {
    int i = blockIdx.x * 256 + threadIdx.x;
    if (i >= npts) return;
    int b = coords[i*4+0];
    int x = coords[i*4+1];
    int y = coords[i*4+2];
    int z = coords[i*4+3];
    int vi = ((b*VXX + x)*VYY + y)*VZZ + z;
    atomicMax(&winner[vi], i);   // max point index == last write wins
}

__global__ void setup_k(const float* __restrict__ wconv,
                        const float* __restrict__ bconv,
                        const float* __restrict__ gamma,
                        const float* __restrict__ beta,
                        const float* __restrict__ mean,
                        const float* __restrict__ var,
                        int4* __restrict__ winner4,
                        ushort* __restrict__ wfrag,
                        float2* __restrict__ bnss) {
    const int b = blockIdx.x, tid = threadIdx.x;
    if (b < 1280) {
        winner4[b*256 + tid] = make_int4(-1, -1, -1, -1);
    } else if (b < 1330) {
        int idx = (b - 1280)*256 + tid;
        int f   = idx >> 9;
        int rem = idx & 511;
        int l   = rem >> 3;
        int j   = rem & 7;
        int mt  = f / 5;
        int ks  = f - mt*5;
        int o   = mt*16 + (l & 15);
        int c   = ks*32 + (l >> 4)*8 + j;
        wfrag[idx] = f2bf(wconv[o*160 + c]);
    } else if (tid < NC) {
        float inv = gamma[tid] * rsqrtf(var[tid] + EPSV);
        bnss[tid] = make_float2(inv, bconv[tid]*inv + beta[tid] - mean[tid]*inv);
    }
}

__launch_bounds__(256, 4)
__global__ void fused2_k(const float* __restrict__ bev,
                         const float* __restrict__ feats,
                         const int*  __restrict__ winner,
                         const ushort* __restrict__ wfrag,
                         const float2* __restrict__ bnss,
                         float* __restrict__ out) {
    __shared__ __align__(16) ushort xb_lds[NS * RSB];   // 10240 B (time-shared)
    __shared__ __align__(16) char   u_lds[20736];       // 20736 B (time-shared)
    __shared__ int idx0_lds[NCELL];                     //   960 B
    __shared__ int idx1_lds[NCELL];                     //   960 B
    __shared__ int slot0_pi[SLOTS];                     //   192 B
    __shared__ int slot1_pi[SLOTS];                     //   192 B
    __shared__ int wcnt0[4];                            //    16 B
    __shared__ int wcnt1[4];                            //    16 B
    ushort* const P_lds  = (ushort*)u_lds;              //  9216 B
    ushort* const Rt_lds = (ushort*)(u_lds + 9216);     // 11520 B
    ushort* const xp_lds = (ushort*)u_lds;              // aliases P/Rt

    const int tid   = threadIdx.x;
    const int bid   = blockIdx.x;
    const int swzb  = (bid & 7) * (NB/8) + (bid >> 3);  // XCD-aware, bijective
    const int t0    = swzb * 2;
    const int sbase0 = t0 * NS;
    const int sbase1 = sbase0 + NS;
    const int sl    = tid & 63;
    const int quarter = tid >> 6;
    const int wv    = quarter, lane = sl;
    const int lrow  = lane & 15, lgrp = lane >> 4;
    const int srow  = wv*16 + lrow;

    // ---------- Shared (both tiles) geometry: same h-row ----------
    const int h   = sbase0 / (OW * OZ);      // 50 tiles per h-row; pairs never cross
    const int w00 = (sbase0 >> 4) % OW;      // tile0: w00..w00+3; tile1: +4
    float posy = (h + 0.5f) * ((float)VYY/(float)OH) - 0.5f;
    posy = fminf(fmaxf(posy, 0.f), (float)(VYY-1));
    const int   y0 = (int)posy;
    const int   y1 = min(y0+1, VYY-1);
    const float fy = posy - (float)y0;

    const int zq = sl & 15;
    float posz = (zq + 0.5f) * ((float)VZZ/(float)OZ) - 0.5f;
    posz = fminf(fmaxf(posz, 0.f), (float)(VZZ-1));
    const int   z0 = (int)posz;
    const int   z1 = min(z0+1, VZZ-1);
    const float fzw = posz - (float)z0;

    // Per-tile x geometry
    const float XS = (float)VXX / (float)OW;
    float posx0f = (w00 + (sl >> 4) + 0.5f)*XS - 0.5f;
    posx0f = fminf(fmaxf(posx0f, 0.f), (float)(VXX-1));
    const int   x00 = (int)posx0f;
    const int   x10 = min(x00+1, VXX-1);
    const float fxw0 = posx0f - (float)x00;
    float pxm0 = (w00 + 0.5f)*XS - 0.5f;
    pxm0 = fminf(fmaxf(pxm0, 0.f), (float)(VXX-1));
    const int xmin0 = (int)pxm0;
    const int fx00 = x00 - xmin0, fx10 = x10 - xmin0;

    float posx1f = (w00 + 4 + (sl >> 4) + 0.5f)*XS - 0.5f;
    posx1f = fminf(fmaxf(posx1f, 0.f), (float)(VXX-1));
    const int   x01 = (int)posx1f;
    const int   x11 = min(x01+1, VXX-1);
    const float fxw1 = posx1f - (float)x01;
    float pxm1 = (w00 + 4 + 0.5f)*XS - 0.5f;
    pxm1 = fminf(fmaxf(pxm1, 0.f), (float)(VXX-1));
    const int xmin1 = (int)pxm1;
    const int fx01 = x01 - xmin1, fx11 = x11 - xmin1;

    // Discovery-cell decomposition
    const int dfz  = tid % VZZ;
    const int dfx  = (tid / VZZ) % X_FOOT;
    const int dfyc = tid / (VZZ * X_FOOT);
    const int dyy  = dfyc ? y1 : y0;

    // ---------- Issue BOTH winner loads first (longest scattered latency) ----------
    int pi0 = -1, pi1 = -1;
    if (tid < NCELL) {
        pi0 = winner[(min(xmin0 + dfx, VXX-1)*VYY + dyy)*VZZ + dfz];
        pi1 = winner[(min(xmin1 + dfx, VXX-1)*VYY + dyy)*VZZ + dfz];
    }
    __builtin_amdgcn_sched_barrier(0);

    // ---------- bev tile0 loads (coalesced, lane = s) ----------
    float bvv[20];
    #pragma unroll
    for (int j = 0; j < 20; ++j)
        bvv[j] = bev[(quarter*20 + j)*SPATIAL + sbase0 + sl];
    __builtin_amdgcn_sched_barrier(0);

    // ---------- P zero (tile0) ----------
    {
        uint* pz = (uint*)u_lds;
        #pragma unroll
        for (int i = 0; i < 9; ++i) pz[tid + i*256] = 0;
    }

    // ---------- Ballot-scan for BOTH tiles ----------
    unsigned long long bm0 = __ballot(pi0 >= 0);
    unsigned long long bm1 = __ballot(pi1 >= 0);
    if (lane == 0) { wcnt0[wv] = __popcll(bm0); wcnt1[wv] = __popcll(bm1); }
    bar_lgkm();                                   // B1 (also: P0 zero visible)
    int base0 = 0, nstot0 = 0, base1 = 0, nstot1 = 0;
    #pragma unroll
    for (int w2 = 0; w2 < 4; ++w2) {
        int c0 = wcnt0[w2], c1 = wcnt1[w2];
        if (w2 < wv) { base0 += c0; base1 += c1; }
        nstot0 += c0; nstot1 += c1;
    }
    if (tid < NCELL) {
        int v0 = -1, v1 = -1;
        if (pi0 >= 0) {
            int s = base0 + __popcll(bm0 & ((1ull << lane) - 1ull));
            if (s < SLOTS) { slot0_pi[s] = pi0; v0 = s; } else v0 = -(pi0 + 2);
        }
        if (pi1 >= 0) {
            int s = base1 + __popcll(bm1 & ((1ull << lane) - 1ull));
            if (s < SLOTS) { slot1_pi[s] = pi1; v1 = s; } else v1 = -(pi1 + 2);
        }
        idx0_lds[tid] = v0;
        idx1_lds[tid] = v1;
    }
    bar_lgkm();                                   // B2
    const int nst0 = min(nstot0, SLOTS);
    const int nst1 = min(nstot1, SLOTS);

    // ---------- Issue feats rows for BOTH tiles (tile1's fly under tile0 compute) ----------
    const float4* feats4 = (const float4*)feats;
    const int myslot = tid >> 2, part = tid & 3;
    const bool rowact0 = (myslot < nst0);
    const bool rowact1 = (myslot < nst1);
    float4 rbuf0[5], rbuf1[5];
    if (rowact0) {
        const float4* p = feats4 + slot0_pi[myslot]*20 + part*5;
        #pragma unroll
        for (int q = 0; q < 5; ++q) rbuf0[q] = p[q];
    }
    if (rowact1) {
        const float4* p = feats4 + slot1_pi[myslot]*20 + part*5;
        #pragma unroll
        for (int q = 0; q < 5; ++q) rbuf1[q] = p[q];
    }
    __builtin_amdgcn_sched_barrier(0);

    // ---------- Tile0: P scatter ----------
    {
        const int ky = quarter >> 1, kx = quarter & 1;
        const float ywp = ky ? fy : 1.f - fy;
        const bool xdup = (fx10 == fx00);
        if (!(xdup && kx)) {
            const int   xf = kx ? fx10 : fx00;
            const float xw = xdup ? 1.f : (kx ? fxw0 : 1.f - fxw0);
            #pragma unroll
            for (int kz = 0; kz < 2; ++kz) {
                int v = idx0_lds[(ky*X_FOOT + xf)*VZZ + (kz ? z1 : z0)];
                if (v >= 0)
                    P_lds[sl*PSTR + v] = f2bf(ywp * xw * (kz ? fzw : 1.f - fzw));
            }
        }
    }

    // ---------- Tile0: xb stage (consumes bvv) ----------
    #pragma unroll
    for (int j5 = 0; j5 < 5; ++j5) {
        ushort4 pk = make_ushort4(f2bf(bvv[j5*4+0]), f2bf(bvv[j5*4+1]),
                                  f2bf(bvv[j5*4+2]), f2bf(bvv[j5*4+3]));
        *(ushort4*)&xb_lds[sl*RSB + quarter*20 + j5*4] = pk;
    }

    // ---------- Issue bev tile1 loads (bvv regs free; fly under tile0 GEMMs) ----------
    #pragma unroll
    for (int j = 0; j < 20; ++j)
        bvv[j] = bev[(quarter*20 + j)*SPATIAL + sbase1 + sl];
    __builtin_amdgcn_sched_barrier(0);

    // ---------- Tile0: Rt commit (consumes rbuf0) ----------
    {
        ushort vals[20];
        #pragma unroll
        for (int q = 0; q < 5; ++q) {
            vals[4*q+0] = rowact0 ? f2bf(rbuf0[q].x) : (ushort)0;
            vals[4*q+1] = rowact0 ? f2bf(rbuf0[q].y) : (ushort)0;
            vals[4*q+2] = rowact0 ? f2bf(rbuf0[q].z) : (ushort)0;
            vals[4*q+3] = rowact0 ? f2bf(rbuf0[q].w) : (ushort)0;
        }
        #pragma unroll
        for (int e = 0; e < 20; ++e)
            Rt_lds[(part*20 + e)*PSTR + myslot] = vals[e];
    }
    bar_lgkm();                                   // B3

    // ---------- Tile0 phase 3: prior = Rt x P^T ----------
    f32x4 pa[5];
    {
        const int prow = srow*PSTR;
        s16x8 p0 = *(const s16x8*)&P_lds[prow +      lgrp*8];
        s16x8 p1 = *(const s16x8*)&P_lds[prow + 32 + lgrp*8];
        #pragma unroll
        for (int mt = 0; mt < 5; ++mt) {
            const int arow = (mt*16 + lrow)*PSTR;
            s16x8 a0 = *(const s16x8*)&Rt_lds[arow +      lgrp*8];
            s16x8 a1 = *(const s16x8*)&Rt_lds[arow + 32 + lgrp*8];
            pa[mt] = (f32x4){0.f, 0.f, 0.f, 0.f};
            pa[mt] = __builtin_amdgcn_mfma_f32_16x16x32_bf16(a0, p0, pa[mt], 0, 0, 0);
            pa[mt] = __builtin_amdgcn_mfma_f32_16x16x32_bf16(a1, p1, pa[mt], 0, 0, 0);
        }
    }
    bar_lgkm();                                   // B4: P/Rt reads drained
    #pragma unroll
    for (int mt = 0; mt < 5; ++mt) {
        ushort4 pk = make_ushort4(f2bf(pa[mt][0]), f2bf(pa[mt][1]),
                                  f2bf(pa[mt][2]), f2bf(pa[mt][3]));
        *(ushort4*)&xp_lds[srow*RSP + mt*16 + lgrp*4] = pk;
    }

    // ---------- Tile0 overflow fallback (cold) ----------
    if (nstot0 > SLOTS) {
        bar_lgkm();
        float add20[20];
        #pragma unroll
        for (int j = 0; j < 20; ++j) add20[j] = 0.f;
        bool any = false;
        #pragma unroll
        for (int k = 0; k < 8; ++k) {
            int kz = k & 1, kx = (k>>1)&1, ky = k>>2;
            int v = idx0_lds[(ky*X_FOOT + (kx ? fx10 : fx00))*VZZ + (kz ? z1 : z0)];
            if (v < -1) {
                any = true;
                float wtk = (ky?fy:1.f-fy) * (kx?fxw0:1.f-fxw0) * (kz?fzw:1.f-fzw);
                const float4* p = feats4 + (-v - 2)*20 + quarter*5;
                #pragma unroll
                for (int q = 0; q < 5; ++q) {
                    float4 f = p[q];
                    add20[4*q]   += wtk*f.x; add20[4*q+1] += wtk*f.y;
                    add20[4*q+2] += wtk*f.z; add20[4*q+3] += wtk*f.w;
                }
            }
        }
        if (any) {
            #pragma unroll
            for (int q = 0; q < 5; ++q) {
                ushort* dst = &xp_lds[sl*RSP + quarter*20 + q*4];
                ushort4 old = *(ushort4*)dst;
                const ushort ov[4] = {old.x, old.y, old.z, old.w};
                ushort nv[4];
                #pragma unroll
                for (int e = 0; e < 4; ++e) {
                    float f = __builtin_bit_cast(float, (uint)ov[e] << 16) + add20[4*q+e];
                    nv[e] = f2bf(f);
                }
                *(ushort4*)dst = make_ushort4(nv[0], nv[1], nv[2], nv[3]);
            }
        }
    }
    bar_lgkm();                                   // B5

    // ---------- Tile0 phase D + epilogue ----------
    {
        f32x4 acc[5];
        #pragma unroll
        for (int mt = 0; mt < 5; ++mt) acc[mt] = (f32x4){0.f, 0.f, 0.f, 0.f};
        const int srow_b = srow * RSB;
        const int srow_p = srow * RSP;
        #pragma unroll
        for (int ks = 0; ks < 5; ++ks) {
            int c = ks*32 + lgrp*8;
            const ushort* bp = (c < 80) ? &xb_lds[srow_b + c]
                                        : &xp_lds[srow_p + (c - 80)];
            s16x8 b = *(const s16x8*)bp;
            #pragma unroll
            for (int mt = 0; mt < 5; ++mt) {
                s16x8 a = *(const s16x8*)&wfrag[((mt*5 + ks)*64 + lane)*8];
                acc[mt] = __builtin_amdgcn_mfma_f32_16x16x32_bf16(a, b, acc[mt], 0, 0, 0);
            }
        }
        const int sglob = sbase0 + srow;
        #pragma unroll
        for (int mt = 0; mt < 5; ++mt) {
            ushort4 rr = *(const ushort4*)&xb_lds[srow_b + mt*16 + lgrp*4];
            const ushort rrv[4] = {rr.x, rr.y, rr.z, rr.w};
            #pragma unroll
            for (int r = 0; r < 4; ++r) {
                int o = mt*16 + lgrp*4 + r;
                float2 ss = bnss[o];
                float resid = __builtin_bit_cast(float, (uint)rrv[r] << 16);
                float v = acc[mt][r]*ss.x + ss.y + resid;
                out[o*SPATIAL + sglob] = fmaxf(v, 0.f);
            }
        }
    }
    bar_lgkm();                                   // B6: xb/xp tile0 dead

    // ================= Tile 1 =================
    // ---------- P zero ----------
    {
        uint* pz = (uint*)u_lds;
        #pragma unroll
        for (int i = 0; i < 9; ++i) pz[tid + i*256] = 0;
    }
    bar_lgkm();                                   // B7: zero visible

    // ---------- P scatter ----------
    {
        const int ky = quarter >> 1, kx = quarter & 1;
        const float ywp = ky ? fy : 1.f - fy;
        const bool xdup = (fx11 == fx01);
        if (!(xdup && kx)) {
            const int   xf = kx ? fx11 : fx01;
            const float xw = xdup ? 1.f : (kx ? fxw1 : 1.f - fxw1);
            #pragma unroll
            for (int kz = 0; kz < 2; ++kz) {
                int v = idx1_lds[(ky*X_FOOT + xf)*VZZ + (kz ? z1 : z0)];
                if (v >= 0)
                    P_lds[sl*PSTR + v] = f2bf(ywp * xw * (kz ? fzw : 1.f - fzw));
            }
        }
    }

    // ---------- xb stage (consumes bvv = bev tile1) ----------
    #pragma unroll
    for (int j5 = 0; j5 < 5; ++j5) {
        ushort4 pk = make_ushort4(f2bf(bvv[j5*4+0]), f2bf(bvv[j5*4+1]),
                                  f2bf(bvv[j5*4+2]), f2bf(bvv[j5*4+3]));
        *(ushort4*)&xb_lds[sl*RSB + quarter*20 + j5*4] = pk;
    }

    // ---------- Rt commit (consumes rbuf1, loaded long ago) ----------
    {
        ushort vals[20];
        #pragma unroll
        for (int q = 0; q < 5; ++q) {
            vals[4*q+0] = rowact1 ? f2bf(rbuf1[q].x) : (ushort)0;
            vals[4*q+1] = rowact1 ? f2bf(rbuf1[q].y) : (ushort)0;
            vals[4*q+2] = rowact1 ? f2bf(rbuf1[q].z) : (ushort)0;
            vals[4*q+3] = rowact1 ? f2bf(rbuf1[q].w) : (ushort)0;
        }
        #pragma unroll
        for (int e = 0; e < 20; ++e)
            Rt_lds[(part*20 + e)*PSTR + myslot] = vals[e];
    }
    bar_lgkm();                                   // B8

    // ---------- Phase 3 ----------
    {
        const int prow = srow*PSTR;
        s16x8 p0 = *(const s16x8*)&P_lds[prow +      lgrp*8];
        s16x8 p1 = *(const s16x8*)&P_lds[prow + 32 + lgrp*8];
        #pragma unroll
        for (int mt = 0; mt < 5; ++mt) {
            const int arow = (mt*16 + lrow)*PSTR;
            s16x8 a0 = *(const s16x8*)&Rt_lds[arow +      lgrp*8];
            s16x8 a1 = *(const s16x8*)&Rt_lds[arow + 32 + lgrp*8];
            pa[mt] = (f32x4){0.f, 0.f, 0.f, 0.f};
            pa[mt] = __builtin_amdgcn_mfma_f32_16x16x32_bf16(a0, p0, pa[mt], 0, 0, 0);
            pa[mt] = __builtin_amdgcn_mfma_f32_16x16x32_bf16(a1, p1, pa[mt], 0, 0, 0);
        }
    }
    bar_lgkm();                                   // B9
    #pragma unroll
    for (int mt = 0; mt < 5; ++mt) {
        ushort4 pk = make_ushort4(f2bf(pa[mt][0]), f2bf(pa[mt][1]),
                                  f2bf(pa[mt][2]), f2bf(pa[mt][3]));
        *(ushort4*)&xp_lds[srow*RSP + mt*16 + lgrp*4] = pk;
    }

    // ---------- Tile1 overflow fallback (cold) ----------
    if (nstot1 > SLOTS) {
        bar_lgkm();
        float add20[20];
        #pragma unroll
        for (int j = 0; j < 20; ++j) add20[j] = 0.f;
        bool any = false;
        #pragma unroll
        for (int k = 0; k < 8; ++k) {
            int kz = k & 1, kx = (k>>1)&1, ky = k>>2;
            int v = idx1_lds[(ky*X_FOOT + (kx ? fx11 : fx01))*VZZ + (kz ? z1 : z0)];
            if (v < -1) {
                any = true;
                float wtk = (ky?fy:1.f-fy) * (kx?fxw1:1.f-fxw1) * (kz?fzw:1.f-fzw);
                const float4* p = feats4 + (-v - 2)*20 + quarter*5;
                #pragma unroll
                for (int q = 0; q < 5; ++q) {
                    float4 f = p[q];
                    add20[4*q]   += wtk*f.x; add20[4*q+1] += wtk*f.y;
                    add20[4*q+2] += wtk*f.z; add20[4*q+3] += wtk*f.w;
                }
            }
        }
        if (any) {
            #pragma unroll
            for (int q = 0; q < 5; ++q) {
                ushort* dst = &xp_lds[sl*RSP + quarter*20 + q*4];
                ushort4 old = *(ushort4*)dst;
                const ushort ov[4] = {old.x, old.y, old.z, old.w};
                ushort nv[4];
                #pragma unroll
                for (int e = 0; e < 4; ++e) {
                    float f = __builtin_bit_cast(float, (uint)ov[e] << 16) + add20[4*q+e];
                    nv[e] = f2bf(f);
                }
                *(ushort4*)dst = make_ushort4(nv[0], nv[1], nv[2], nv[3]);
            }
        }
    }
    bar_lgkm();                                   // B10

    // ---------- Tile1 phase D + epilogue ----------
    {
        f32x4 acc[5];
        #pragma unroll
        for (int mt = 0; mt < 5; ++mt) acc[mt] = (f32x4){0.f, 0.f, 0.f, 0.f};
        const int srow_b = srow * RSB;
        const int srow_p = srow * RSP;
        #pragma unroll
        for (int ks = 0; ks < 5; ++ks) {
            int c = ks*32 + lgrp*8;
            const ushort* bp = (c < 80) ? &xb_lds[srow_b + c]
                                        : &xp_lds[srow_p + (c - 80)];
            s16x8 b = *(const s16x8*)bp;
            #pragma unroll
            for (int mt = 0; mt < 5; ++mt) {
                s16x8 a = *(const s16x8*)&wfrag[((mt*5 + ks)*64 + lane)*8];
                acc[mt] = __builtin_amdgcn_mfma_f32_16x16x32_bf16(a, b, acc[mt], 0, 0, 0);
            }
        }
        const int sglob = sbase1 + srow;
        #pragma unroll
        for (int mt = 0; mt < 5; ++mt) {
            ushort4 rr = *(const ushort4*)&xb_lds[srow_b + mt*16 + lgrp*4];
            const ushort rrv[4] = {rr.x, rr.y, rr.z, rr.w};
            #pragma unroll
            for (int r = 0; r < 4; ++r) {
                int o = mt*16 + lgrp*4 + r;
                float2 ss = bnss[o];
                float resid = __builtin_bit_cast(float, (uint)rrv[r] << 16);
                float v = acc[mt][r]*ss.x + ss.y + resid;
                out[o*SPATIAL + sglob] = fmaxf(v, 0.f);
            }
        }
    }
}

extern "C" void kernel_launch(void* const* d_in, const int* in_sizes, int n_in,
                              void* d_out, int out_size, void* d_ws, size_t ws_size,
                              hipStream_t stream) {
    const float* bev    = (const float*)d_in[0];
    const int*   coords = (const int*)  d_in[1];
    const float* feats  = (const float*)d_in[2];
    const float* wconv  = (const float*)d_in[3];
    const float* bconv  = (const float*)d_in[4];
    const float* gamma  = (const float*)d_in[5];
    const float* beta   = (const float*)d_in[6];
    const float* mean   = (const float*)d_in[7];
    const float* var    = (const float*)d_in[8];
    float*       out    = (float*)d_out;

    int*    winner = (int*)d_ws;                                      // 5,242,880 B
    ushort* wfrag  = (ushort*)((char*)d_ws + (size_t)NVOX*4);         // 25,600 B
    float2* bnss   = (float2*)((char*)d_ws + (size_t)NVOX*4 + 25600); // 640 B
    int npts = in_sizes[1] / 4;

    hipLaunchKernelGGL(setup_k, dim3(1331), dim3(256), 0, stream,
                       wconv, bconv, gamma, beta, mean, var,
                       (int4*)winner, wfrag, bnss);
    hipLaunchKernelGGL(scatter_k, dim3((npts + 255)/256), dim3(256), 0, stream,
                       coords, npts, winner);
    hipLaunchKernelGGL(fused2_k, dim3(NB), dim3(256), 0, stream,
                       bev, feats, winner, wfrag, bnss, out);
}

// Round 20
// 149.659 us; speedup vs baseline: 1.3244x; 1.3244x over previous
//
#include <hip/hip_runtime.h>
#include <hip/hip_bf16.h>

#define VXX 256
#define VYY 256
#define VZZ 20
#define NC  80
#define OH  200
#define OW  200
#define OZ  16
#define SPATIAL (OH*OW*OZ)      // 640000
#define NVOX (VXX*VYY*VZZ)      // 1310720
#define EPSV 1e-5f
#define NS 64                   // spatial positions per block
#define RS 168                  // x_lds row stride in bf16 elems (336 B)
#define NWG (SPATIAL/NS)        // 10000 blocks
#define X_FOOT 6                // max distinct x in a block's tap footprint
#define NCELL (2*X_FOOT*VZZ)    // 240 footprint cells
#define SLOTS 48                // staged feats rows (occupied mean ~34, sd ~5.4)
#define PSTR 72                 // bf16 per P/Rt row (64 K + 8 pad; 144 B, 16B-aligned)

typedef float  f32x4 __attribute__((ext_vector_type(4)));
typedef short  s16x8 __attribute__((ext_vector_type(8)));

__device__ __forceinline__ ushort f2bf(float f) {
    uint u = __builtin_bit_cast(uint, f);
    u += 0x7FFFu + ((u >> 16) & 1u);     // round-to-nearest-even
    return (ushort)(u >> 16);
}

// Barrier that drains ONLY LDS ops (all cross-thread deps in fused_k are LDS).
__device__ __forceinline__ void bar_lgkm() {
    asm volatile("s_waitcnt lgkmcnt(0)" ::: "memory");
    __builtin_amdgcn_s_barrier();
    asm volatile("" ::: "memory");
}

__global__ void scatter_k(const int* __restrict__ coords, int npts,
                          int* __restrict__ winner) {
    int i = blockIdx.x * 256 + threadIdx.x;
    if (i >= npts) return;
    int b = coords[i*4+0];
    int x = coords[i*4+1];
    int y = coords[i*4+2];
    int z = coords[i*4+3];
    int vi = ((b*VXX + x)*VYY + y)*VZZ + z;
    atomicMax(&winner[vi], i);   // max point index == last write wins
}

// Merged: winner init (blocks 0..1279), W-fragment pack (1280..1329), BN fold (1330).
__global__ void setup_k(const float* __restrict__ wconv,
                        const float* __restrict__ bconv,
                        const float* __restrict__ gamma,
                        const float* __restrict__ beta,
                        const float* __restrict__ mean,
                        const float* __restrict__ var,
                        int4* __restrict__ winner4,
                        ushort* __restrict__ wfrag,
                        float2* __restrict__ bnss) {
    const int b = blockIdx.x, tid = threadIdx.x;
    if (b < 1280) {
        winner4[b*256 + tid] = make_int4(-1, -1, -1, -1);   // NVOX/4 = 327680
    } else if (b < 1330) {
        int idx = (b - 1280)*256 + tid;    // < 12800
        int f   = idx >> 9;
        int rem = idx & 511;
        int l   = rem >> 3;
        int j   = rem & 7;
        int mt  = f / 5;
        int ks  = f - mt*5;
        int o   = mt*16 + (l & 15);
        int c   = ks*32 + (l >> 4)*8 + j;
        wfrag[idx] = f2bf(wconv[o*160 + c]);
    } else if (tid < NC) {
        float inv = gamma[tid] * rsqrtf(var[tid] + EPSV);
        bnss[tid] = make_float2(inv, bconv[tid]*inv + beta[tid] - mean[tid]*inv);
    }
}

__launch_bounds__(256, 3)
__global__ void fused_k(const float* __restrict__ bev,
                        const float* __restrict__ feats,
                        const int*  __restrict__ winner,
                        const ushort* __restrict__ wfrag,
                        const float2* __restrict__ bnss,
                        float* __restrict__ out) {
    __shared__ __align__(16) ushort x_lds[NS * RS];     // 21504 B
    __shared__ __align__(16) ushort P_lds[NS * PSTR];   //  9216 B: tap weights [s][slot]
    __shared__ __align__(16) ushort Rt_lds[NC * PSTR];  // 11520 B: feats rows  [c][slot]
    __shared__ int    idx_lds[NCELL];                   //   960 B: slot / -1 / -(pi+2)
    __shared__ int    slot_pi[SLOTS];                   //   192 B
    __shared__ int    wavecnt[4];                       //    16 B

    const int tid   = threadIdx.x;
    const int bid   = blockIdx.x;
    const int swzb  = (bid & 7) * (NWG/8) + (bid >> 3);  // XCD-aware, bijective
    const int sbase = swzb * NS;
    const int sl    = tid & 63;
    const int quarter = tid >> 6;
    const int wv    = quarter, lane = sl;

    // ---------- Block-uniform geometry ----------
    const int h  = sbase / (OW * OZ);
    const int w0 = (sbase >> 4) % OW;     // block spans w0..w0+3, no row crossing
    float posy = (h + 0.5f) * ((float)VYY/(float)OH) - 0.5f;
    posy = fminf(fmaxf(posy, 0.f), (float)(VYY-1));
    const int   y0 = (int)posy;
    const int   y1 = min(y0+1, VYY-1);
    const float fy = posy - (float)y0;
    float posx0 = (w0 + 0.5f) * ((float)VXX/(float)OW) - 0.5f;
    posx0 = fminf(fmaxf(posx0, 0.f), (float)(VXX-1));
    const int xmin = (int)posx0;          // footprint x in [xmin, xmin+5]

    // ---------- Per-thread (s) tap geometry ----------
    const int zq = sl & 15;
    const int wq = w0 + (sl >> 4);
    float posx = (wq + 0.5f) * ((float)VXX/(float)OW) - 0.5f;
    posx = fminf(fmaxf(posx, 0.f), (float)(VXX-1));
    const int   x0 = (int)posx;
    const int   x1 = min(x0+1, VXX-1);
    const float fxw = posx - (float)x0;
    float posz = (zq + 0.5f) * ((float)VZZ/(float)OZ) - 0.5f;
    posz = fminf(fmaxf(posz, 0.f), (float)(VZZ-1));
    const int   z0 = (int)posz;
    const int   z1 = min(z0+1, VZZ-1);
    const float fzw = posz - (float)z0;
    const int fx0 = x0 - xmin, fx1 = x1 - xmin;   // in [0,5]

    // ---------- Issue winner load FIRST (oldest in vmem queue) ----------
    int pi = -1;
    if (tid < NCELL) {
        int fz  = tid % VZZ;
        int fx  = (tid / VZZ) % X_FOOT;
        int fyc = tid / (VZZ * X_FOOT);
        int xx  = min(xmin + fx, VXX-1);
        int yy  = fyc ? y1 : y0;
        pi = winner[(xx*VYY + yy)*VZZ + fz];
    }
    __builtin_amdgcn_sched_barrier(0);    // keep winner load ahead of bev loads

    // ---------- Issue bev loads: 20 scalar coalesced dwords (lane = s) ----------
    const int S = sbase + sl;
    float bvv[20];
    #pragma unroll
    for (int j = 0; j < 20; ++j)
        bvv[j] = bev[(quarter*20 + j)*SPATIAL + S];
    __builtin_amdgcn_sched_barrier(0);    // pin loads above the ballot/barriers

    // ---------- P zero (hides under winner latency) ----------
    {
        uint* pz = (uint*)P_lds;          // 2304 dwords
        #pragma unroll
        for (int i = 0; i < 9; ++i) pz[tid + i*256] = 0;
    }

    // ---------- Phase 1: ballot-scan slot allocation ----------
    unsigned long long bm = __ballot(pi >= 0);
    if (lane == 0) wavecnt[wv] = __popcll(bm);
    bar_lgkm();
    int base = 0, nstot = 0;
    #pragma unroll
    for (int w2 = 0; w2 < 4; ++w2) {
        int c2 = wavecnt[w2];
        if (w2 < wv) base += c2;
        nstot += c2;
    }
    if (tid < NCELL) {
        int v = -1;
        if (pi >= 0) {
            int slot = base + __popcll(bm & ((1ull << lane) - 1ull));
            if (slot < SLOTS) { slot_pi[slot] = pi; v = slot; }
            else v = -(pi + 2);            // overflow: direct-global fallback
        }
        idx_lds[tid] = v;
    }
    bar_lgkm();
    const int nst = min(nstot, SLOTS);

    // ---------- Phase 2a: issue feats row loads (4 threads/slot x 5 float4) ----------
    const float4* feats4 = (const float4*)feats;
    const int myslot = tid >> 2, part = tid & 3;   // myslot 0..63
    const bool rowact = (myslot < nst);
    float4 rbuf[5];
    if (rowact) {
        const float4* p = feats4 + slot_pi[myslot]*20 + part*5;
        #pragma unroll
        for (int q = 0; q < 5; ++q) rbuf[q] = p[q];
    }

    // ---------- Phase 2b: P scatter (thread (s, quarter) owns taps 2q, 2q+1) ----------
    {
        const int ky = quarter >> 1, kx = quarter & 1;
        const float ywp = ky ? fy : 1.f - fy;
        const bool xdup = (fx1 == fx0);   // statically never at these shapes; kept safe
        if (!(xdup && kx)) {
            const int   xf = kx ? fx1 : fx0;
            const float xw = xdup ? 1.f : (kx ? fxw : 1.f - fxw);
            #pragma unroll
            for (int kz = 0; kz < 2; ++kz) {
                int cell = (ky*X_FOOT + xf)*VZZ + (kz ? z1 : z0);
                int v = idx_lds[cell];
                if (v >= 0)
                    P_lds[sl*PSTR + v] = f2bf(ywp * xw * (kz ? fzw : 1.f - fzw));
            }
        }
    }

    // ---------- Phase 2c: stage bev -> x_lds[s][0..79] ----------
    #pragma unroll
    for (int j5 = 0; j5 < 5; ++j5) {
        ushort4 pk = make_ushort4(f2bf(bvv[j5*4+0]), f2bf(bvv[j5*4+1]),
                                  f2bf(bvv[j5*4+2]), f2bf(bvv[j5*4+3]));
        *(ushort4*)&x_lds[sl*RS + quarter*20 + j5*4] = pk;
    }

    // ---------- Phase 2d: commit feats rows transposed -> Rt[c][slot] ----------
    // All 64 slot-columns [0,64) covered: real rows for slot<nst, zeros for the
    // K-pad gap (so MFMA's k in [0,64) never reads garbage/NaN).
    {
        ushort vals[20];
        #pragma unroll
        for (int q = 0; q < 5; ++q) {
            vals[4*q+0] = rowact ? f2bf(rbuf[q].x) : (ushort)0;
            vals[4*q+1] = rowact ? f2bf(rbuf[q].y) : (ushort)0;
            vals[4*q+2] = rowact ? f2bf(rbuf[q].z) : (ushort)0;
            vals[4*q+3] = rowact ? f2bf(rbuf[q].w) : (ushort)0;
        }
        #pragma unroll
        for (int e = 0; e < 20; ++e)
            Rt_lds[(part*20 + e)*PSTR + myslot] = vals[e];
    }
    bar_lgkm();

    // ---------- Phase 3: prior = Rt x P^T via MFMA -> x_lds[s][80..159] ----------
    const int lrow = lane & 15, lgrp = lane >> 4;
    {
        const int prow = (wv*16 + lrow)*PSTR;
        s16x8 p0 = *(const s16x8*)&P_lds[prow +      lgrp*8];
        s16x8 p1 = *(const s16x8*)&P_lds[prow + 32 + lgrp*8];
        #pragma unroll
        for (int mt = 0; mt < 5; ++mt) {
            const int arow = (mt*16 + lrow)*PSTR;
            s16x8 a0 = *(const s16x8*)&Rt_lds[arow +      lgrp*8];
            s16x8 a1 = *(const s16x8*)&Rt_lds[arow + 32 + lgrp*8];
            f32x4 pa = (f32x4){0.f, 0.f, 0.f, 0.f};
            pa = __builtin_amdgcn_mfma_f32_16x16x32_bf16(a0, p0, pa, 0, 0, 0);
            pa = __builtin_amdgcn_mfma_f32_16x16x32_bf16(a1, p1, pa, 0, 0, 0);
            // D: col = lane&15 = s_local, row = c = mt*16 + lgrp*4 + r
            ushort4 pk = make_ushort4(f2bf(pa[0]), f2bf(pa[1]),
                                      f2bf(pa[2]), f2bf(pa[3]));
            *(ushort4*)&x_lds[(wv*16 + lrow)*RS + 80 + mt*16 + lgrp*4] = pk;
        }
    }

    // ---------- Overflow fallback (block-uniform, ~never taken) ----------
    if (nstot > SLOTS) {
        bar_lgkm();
        float add20[20];
        #pragma unroll
        for (int j = 0; j < 20; ++j) add20[j] = 0.f;
        bool any = false;
        #pragma unroll
        for (int k = 0; k < 8; ++k) {
            int kz = k & 1, kx = (k>>1)&1, ky = k>>2;
            int cell = (ky*X_FOOT + (kx ? fx1 : fx0))*VZZ + (kz ? z1 : z0);
            int v = idx_lds[cell];
            if (v < -1) {
                any = true;
                float wtk = (ky?fy:1.f-fy) * (kx?fxw:1.f-fxw) * (kz?fzw:1.f-fzw);
                const float4* p = feats4 + (-v - 2)*20 + quarter*5;
                #pragma unroll
                for (int q = 0; q < 5; ++q) {
                    float4 f = p[q];
                    add20[4*q]   += wtk*f.x; add20[4*q+1] += wtk*f.y;
                    add20[4*q+2] += wtk*f.z; add20[4*q+3] += wtk*f.w;
                }
            }
        }
        if (any) {
            #pragma unroll
            for (int q = 0; q < 5; ++q) {
                ushort* dst = &x_lds[sl*RS + 80 + quarter*20 + q*4];
                ushort4 old = *(ushort4*)dst;
                const ushort ov[4] = {old.x, old.y, old.z, old.w};
                ushort nv[4];
                #pragma unroll
                for (int e = 0; e < 4; ++e) {
                    float f = __builtin_bit_cast(float, (uint)ov[e] << 16) + add20[4*q+e];
                    nv[e] = f2bf(f);
                }
                *(ushort4*)dst = make_ushort4(nv[0], nv[1], nv[2], nv[3]);
            }
        }
    }
    bar_lgkm();

    // ---------- Phase D: MFMA GEMM  y[o][s] = sum_c W[o][c] * x[c][s] ----------
    f32x4 acc[5];
    #pragma unroll
    for (int mt = 0; mt < 5; ++mt) acc[mt] = (f32x4){0.f, 0.f, 0.f, 0.f};

    const int srow = (wv*16 + lrow) * RS;   // each wave owns a 16-s tile

    #pragma unroll
    for (int ks = 0; ks < 5; ++ks) {
        s16x8 b = *(const s16x8*)&x_lds[srow + ks*32 + lgrp*8];
        #pragma unroll
        for (int mt = 0; mt < 5; ++mt) {
            s16x8 a = *(const s16x8*)&wfrag[((mt*5 + ks)*64 + lane)*8];
            acc[mt] = __builtin_amdgcn_mfma_f32_16x16x32_bf16(a, b, acc[mt], 0, 0, 0);
        }
    }

    // ---------- Epilogue: BN + residual (batched b64 LDS read) + ReLU ----------
    const int slocal = wv*16 + lrow;
    const int sglob  = sbase + slocal;
    #pragma unroll
    for (int mt = 0; mt < 5; ++mt) {
        ushort4 rr = *(const ushort4*)&x_lds[slocal*RS + mt*16 + lgrp*4];
        const ushort rrv[4] = {rr.x, rr.y, rr.z, rr.w};
        #pragma unroll
        for (int r = 0; r < 4; ++r) {
            int o = mt*16 + lgrp*4 + r;
            float2 ss = bnss[o];
            float resid = __builtin_bit_cast(float, (uint)rrv[r] << 16);
            float v = acc[mt][r]*ss.x + ss.y + resid;
            out[o*SPATIAL + sglob] = fmaxf(v, 0.f);
        }
    }
}

extern "C" void kernel_launch(void* const* d_in, const int* in_sizes, int n_in,
                              void* d_out, int out_size, void* d_ws, size_t ws_size,
                              hipStream_t stream) {
    const float* bev    = (const float*)d_in[0];
    const int*   coords = (const int*)  d_in[1];
    const float* feats  = (const float*)d_in[2];
    const float* wconv  = (const float*)d_in[3];
    const float* bconv  = (const float*)d_in[4];
    const float* gamma  = (const float*)d_in[5];
    const float* beta   = (const float*)d_in[6];
    const float* mean   = (const float*)d_in[7];
    const float* var    = (const float*)d_in[8];
    float*       out    = (float*)d_out;

    int*    winner = (int*)d_ws;                                      // 5,242,880 B
    ushort* wfrag  = (ushort*)((char*)d_ws + (size_t)NVOX*4);         // 25,600 B
    float2* bnss   = (float2*)((char*)d_ws + (size_t)NVOX*4 + 25600); // 640 B
    int npts = in_sizes[1] / 4;

    hipLaunchKernelGGL(setup_k, dim3(1331), dim3(256), 0, stream,
                       wconv, bconv, gamma, beta, mean, var,
                       (int4*)winner, wfrag, bnss);
    hipLaunchKernelGGL(scatter_k, dim3((npts + 255)/256), dim3(256), 0, stream,
                       coords, npts, winner);
    hipLaunchKernelGGL(fused_k, dim3(NWG), dim3(256), 0, stream,
                       bev, feats, winner, wfrag, bnss, out);
}